// Round 1
// baseline (273.581 us; speedup 1.0000x reference)
//
#include <hip/hip_runtime.h>
#include <hip/hip_bf16.h>
#include <string.h>

#define GAMMA 0.015625f
#define D 64

typedef short bf16x8 __attribute__((ext_vector_type(8)));   // 8 bf16 = 4 VGPRs
typedef float floatx4 __attribute__((ext_vector_type(4)));

// ---------------------------------------------------------------------------
// Prep: fp32 [rows,64] -> bf16 [rows,64] + fp32 row norms (of the ROUNDED
// values, so d2 = xsq + ysq - 2*cross is the exact distance of the bf16
// vectors, guaranteed >= 0 up to fp32 roundoff).
// One wave (64 lanes) per row: lane k handles element k. 4 rows per block.
// ---------------------------------------------------------------------------
__global__ __launch_bounds__(256) void prep_kernel(const float* __restrict__ src,
                                                   short* __restrict__ dst,
                                                   float* __restrict__ norms,
                                                   int nrows) {
    int wave = threadIdx.x >> 6;
    int lane = threadIdx.x & 63;
    int row  = blockIdx.x * 4 + wave;
    if (row >= nrows) return;
    float v = src[(size_t)row * D + lane];
    __hip_bfloat16 b = __float2bfloat16(v);
    short bs;
    memcpy(&bs, &b, sizeof(short));
    dst[(size_t)row * D + lane] = bs;
    float bv = __bfloat162float(b);
    float sq = bv * bv;
#pragma unroll
    for (int off = 32; off > 0; off >>= 1) sq += __shfl_down(sq, off, 64);
    if (lane == 0) norms[row] = sq;
}

// ---------------------------------------------------------------------------
// Fused RBF GEMM: 128x128 block tile, 4 waves in 2x2, each wave 64x64.
// Fragments loaded straight from global (row-major, K contiguous): for
// mfma_f32_16x16x32_bf16, lane holds A[m=lane&15][k=quad*8+j] -> one 16B load.
// B = sv^T so B[k][n] = sv[n][k]: identical row-load pattern.
// C/D layout: col = lane&15, row = quad*4 + reg.
// ---------------------------------------------------------------------------
__global__ __launch_bounds__(256) void rbf_gemm(const short* __restrict__ A,
                                                const short* __restrict__ B,
                                                const float* __restrict__ xsq,
                                                const float* __restrict__ ysq,
                                                float* __restrict__ out,
                                                int M) {
    const int wid  = threadIdx.x >> 6;
    const int lane = threadIdx.x & 63;
    const int quad = lane >> 4;
    const int l16  = lane & 15;

    const long row0 = (long)blockIdx.y * 128 + (wid >> 1) * 64;
    const long col0 = (long)blockIdx.x * 128 + (wid & 1) * 64;

    bf16x8 af[4][2], bfr[4][2];
#pragma unroll
    for (int mb = 0; mb < 4; ++mb) {
        const bf16x8* p = (const bf16x8*)(A + (row0 + mb * 16 + l16) * D + quad * 8);
        af[mb][0] = p[0];   // k = quad*8 + [0,8)
        af[mb][1] = p[4];   // k = 32 + quad*8 + [0,8)
    }
#pragma unroll
    for (int nb = 0; nb < 4; ++nb) {
        const bf16x8* p = (const bf16x8*)(B + (col0 + nb * 16 + l16) * D + quad * 8);
        bfr[nb][0] = p[0];
        bfr[nb][1] = p[4];
    }

    floatx4 acc[4][4];
#pragma unroll
    for (int mb = 0; mb < 4; ++mb)
#pragma unroll
        for (int nb = 0; nb < 4; ++nb)
            acc[mb][nb] = (floatx4){0.f, 0.f, 0.f, 0.f};

#pragma unroll
    for (int k = 0; k < 2; ++k)
#pragma unroll
        for (int mb = 0; mb < 4; ++mb)
#pragma unroll
            for (int nb = 0; nb < 4; ++nb)
                acc[mb][nb] = __builtin_amdgcn_mfma_f32_16x16x32_bf16(
                    af[mb][k], bfr[nb][k], acc[mb][nb], 0, 0, 0);

    // Epilogue: d2 = xsq + ysq - 2*cross, clamped; out = exp(-gamma*d2).
#pragma unroll
    for (int mb = 0; mb < 4; ++mb) {
        const float4 xn4 = *(const float4*)(xsq + row0 + mb * 16 + quad * 4);
        const float xn[4] = {xn4.x, xn4.y, xn4.z, xn4.w};
#pragma unroll
        for (int nb = 0; nb < 4; ++nb) {
            const long col = col0 + nb * 16 + l16;
            const float yn = ysq[col];
#pragma unroll
            for (int r = 0; r < 4; ++r) {
                const long row = row0 + mb * 16 + quad * 4 + r;
                float d2 = fmaxf(xn[r] + yn - 2.0f * acc[mb][nb][r], 0.0f);
                out[row * (long)M + col] = __expf(-GAMMA * d2);
            }
        }
    }
}

// ---------------------------------------------------------------------------
// Fallback (only if ws_size is too small for the bf16 staging buffers):
// direct fp32 distance, compute-bound but correct.
// ---------------------------------------------------------------------------
__global__ __launch_bounds__(256) void rbf_naive(const float* __restrict__ X,
                                                 const float* __restrict__ Y,
                                                 float* __restrict__ out,
                                                 int N, int M) {
    long idx = (long)blockIdx.x * blockDim.x + threadIdx.x;
    if (idx >= (long)N * M) return;
    long i = idx / M, j = idx % M;
    float s = 0.0f;
#pragma unroll
    for (int k = 0; k < D; ++k) {
        float d = X[i * D + k] - Y[j * D + k];
        s = fmaf(d, d, s);
    }
    out[idx] = __expf(-GAMMA * s);
}

extern "C" void kernel_launch(void* const* d_in, const int* in_sizes, int n_in,
                              void* d_out, int out_size, void* d_ws, size_t ws_size,
                              hipStream_t stream) {
    const float* data = (const float*)d_in[0];
    const float* sv   = (const float*)d_in[1];
    float* out = (float*)d_out;
    const int N = in_sizes[0] / D;   // 8192
    const int M = in_sizes[1] / D;   // 8192

    const size_t bfA   = (size_t)N * D * sizeof(short);
    const size_t bfB   = (size_t)M * D * sizeof(short);
    const size_t nrmA  = (size_t)N * sizeof(float);
    const size_t nrmB  = (size_t)M * sizeof(float);
    const size_t need  = bfA + bfB + nrmA + nrmB;

    if (ws_size >= need && (N % 128) == 0 && (M % 128) == 0) {
        char* ws = (char*)d_ws;
        short* Abf = (short*)ws;
        short* Bbf = (short*)(ws + bfA);
        float* xsq = (float*)(ws + bfA + bfB);
        float* ysq = xsq + N;

        hipLaunchKernelGGL(prep_kernel, dim3((N + 3) / 4), dim3(256), 0, stream,
                           data, Abf, xsq, N);
        hipLaunchKernelGGL(prep_kernel, dim3((M + 3) / 4), dim3(256), 0, stream,
                           sv, Bbf, ysq, M);
        dim3 grid(M / 128, N / 128);
        hipLaunchKernelGGL(rbf_gemm, grid, dim3(256), 0, stream,
                           Abf, Bbf, xsq, ysq, out, M);
    } else {
        long total = (long)N * M;
        long blocks = (total + 255) / 256;
        hipLaunchKernelGGL(rbf_naive, dim3((unsigned)blocks), dim3(256), 0, stream,
                           data, sv, out, N, M);
    }
}